// Round 6
// baseline (4482.386 us; speedup 1.0000x reference)
//
#include <hip/hip_runtime.h>
#include <hip/hip_bf16.h>

#define B 64
#define T 8192
#define D 16
#define H 128
#define F 17        // D + 1 features
#define NTHREADS 512
#define CHUNK 32
#define XSTR 40     // xs row stride in halfs (80 B) — bank-friendly
#define GSTR 516    // gi row stride in floats (16B-aligned, mostly conflict-free)

typedef _Float16 half_t;
typedef _Float16 f16x8 __attribute__((ext_vector_type(8)));
typedef _Float16 f16x2 __attribute__((ext_vector_type(2)));
typedef float f32x4 __attribute__((ext_vector_type(4)));

#define MFMA(a, b, c) __builtin_amdgcn_mfma_f32_16x16x32_f16((a), (b), (c), 0, 0, 0)

__device__ __forceinline__ float fast_rcp(float x) {
#if __has_builtin(__builtin_amdgcn_rcpf)
  return __builtin_amdgcn_rcpf(x);
#else
  return 1.0f / x;
#endif
}
__device__ __forceinline__ float fast_exp2(float x) {
#if __has_builtin(__builtin_amdgcn_exp2f)
  return __builtin_amdgcn_exp2f(x);
#else
  return exp2f(x);
#endif
}
__device__ __forceinline__ float fdot2(f16x2 a, f16x2 b, float c) {
#if __has_builtin(__builtin_amdgcn_fdot2)
  return __builtin_amdgcn_fdot2(a, b, c, false);
#else
  return c + (float)a.x * (float)b.x + (float)a.y * (float)b.y;
#endif
}
// pair i (0..3) of a f16x8 == VGPR i of its 4-reg tuple: free extraction
__device__ __forceinline__ f16x2 pick2(f16x8 v, int i) {
  return f16x2{v[2 * i], v[2 * i + 1]};
}

// One GRU step, pure-VALU matvec. Lane (w,mg,jn): owns column jj=w*16+jn,
// k-chunk [32mg,32mg+32). 48 fdot2 -> shfl_xor reduce -> gates -> h write.
#define GSTEP(RB, WB, TT)                                                    \
  do {                                                                       \
    const f32x4 gv = *(const f32x4*)(gi_lds + ((TT) & 31) * GSTR + jj * 4);  \
    const f16x8* hp = (const f16x8*)((RB) + mg * 32);                        \
    const f16x8 hA = hp[0], hB = hp[1], hC = hp[2], hD = hp[3];              \
    float r0=0,r1=0,r2=0,r3=0, z0=0,z1=0,z2=0,z3=0, n0=0,n1=0,n2=0,n3=0;     \
    _Pragma("unroll")                                                        \
    for (int i = 0; i < 4; ++i) {                                            \
      f16x2 pA = pick2(hA, i), pB = pick2(hB, i),                            \
            pC = pick2(hC, i), pD = pick2(hD, i);                            \
      r0 = fdot2(pA, whr[i     ], r0); z0 = fdot2(pA, whz[i     ], z0);      \
      n0 = fdot2(pA, whn[i     ], n0);                                       \
      r1 = fdot2(pB, whr[i +  4], r1); z1 = fdot2(pB, whz[i +  4], z1);      \
      n1 = fdot2(pB, whn[i +  4], n1);                                       \
      r2 = fdot2(pC, whr[i +  8], r2); z2 = fdot2(pC, whz[i +  8], z2);      \
      n2 = fdot2(pC, whn[i +  8], n2);                                       \
      r3 = fdot2(pD, whr[i + 12], r3); z3 = fdot2(pD, whz[i + 12], z3);      \
      n3 = fdot2(pD, whn[i + 12], n3);                                       \
    }                                                                        \
    float sr = (r0 + r1) + (r2 + r3);                                        \
    float sz = (z0 + z1) + (z2 + z3);                                        \
    float sn = (n0 + n1) + (n2 + n3);                                        \
    sr += __shfl_xor(sr, 16, 64); sr += __shfl_xor(sr, 32, 64);              \
    sz += __shfl_xor(sz, 16, 64); sz += __shfl_xor(sz, 32, 64);              \
    sn += __shfl_xor(sn, 16, 64); sn += __shfl_xor(sn, 32, 64);              \
    float rr = fast_rcp(1.0f + fast_exp2(-(sr + gv[0])));                    \
    float zz = fast_rcp(1.0f + fast_exp2(-(sz + gv[1])));                    \
    float pre = fmaf(rr, sn + bn2, gv[2]);                                   \
    pre = fminf(fmaxf(pre, -40.0f), 40.0f);                                  \
    float e = fast_exp2(-pre);                                               \
    float nn = (1.0f - e) * fast_rcp(1.0f + e);                              \
    hreg = fmaf(zz, hreg - nn, nn);  /* (1-z)*n + z*h */                     \
    if (mg == 0) (WB)[jj] = (half_t)hreg;                                    \
    __syncthreads();                                                         \
  } while (0)

__global__ __launch_bounds__(NTHREADS, 1)
void policy_gru_kernel(const float* __restrict__ particles,
                       const float* __restrict__ weights,
                       const float* __restrict__ Wi, const float* __restrict__ Wh,
                       const float* __restrict__ bh,
                       const float* __restrict__ W1, const float* __restrict__ b1,
                       const float* __restrict__ W2, const float* __restrict__ b2,
                       const float* __restrict__ W3, const float* __restrict__ b3,
                       const float* __restrict__ log_std,
                       float* __restrict__ out)
{
  __shared__ __align__(16) half_t hb[2][H];              // h double buffer
  __shared__ __align__(16) half_t xs[CHUNK * XSTR];      // staged X chunk (f16)
  __shared__ __align__(16) float gi_lds[CHUNK * GSTR];   // gi[tau][j*4+{r,z,n,pad}]
  __shared__ float sg[NTHREADS];
  __shared__ float red[8];

  const int tid = threadIdx.x;
  const int b   = blockIdx.x;
  const int l   = tid & 63;
  const int w   = tid >> 6;      // wave 0..7 owns cols w*16..w*16+15
  const int mg  = l >> 4;        // k-quarter 0..3
  const int jn  = l & 15;
  const int jj  = w * 16 + jn;   // hidden unit owned by this lane

  const float L1 = 1.4426950408889634f;   // log2(e)
  const float L2 = 2.0f * L1;

  // ---- per-lane Wh chunk: 3 gates x 32 k as f16 pairs (48 VGPRs) ----
  f16x2 whr[16], whz[16], whn[16];
  #pragma unroll
  for (int i = 0; i < 16; ++i) {
    const int k = mg * 32 + 2 * i;
    whr[i] = f16x2{(half_t)(Wh[k * 384 + jj] * L1),
                   (half_t)(Wh[(k + 1) * 384 + jj] * L1)};
    whz[i] = f16x2{(half_t)(Wh[k * 384 + 128 + jj] * L1),
                   (half_t)(Wh[(k + 1) * 384 + 128 + jj] * L1)};
    whn[i] = f16x2{(half_t)(Wh[k * 384 + 256 + jj] * L2),
                   (half_t)(Wh[(k + 1) * 384 + 256 + jj] * L2)};
  }
  const float bn2 = bh[256 + jj] * L2;

  // ---- Wi B-fragments for the chunk gi matmul (MFMA), K padded 17->32 ----
  auto wiload = [&](int gate) -> f16x8 {
    f16x8 v;
    const float sc  = (gate == 2) ? L2 : L1;
    const int   col = gate * H + jj;
    #pragma unroll
    for (int i = 0; i < 8; ++i) {
      const int k = mg * 8 + i;
      v[i] = (half_t)(k < F ? Wi[k * 384 + col] * sc : 0.0f);
    }
    return v;
  };
  const f16x8 wiR = wiload(0), wiZ = wiload(1), wiN = wiload(2);
  const float br = bh[jj] * L1, bz = bh[128 + jj] * L1;

  // ---- X chunk prefetch: 544 elements over 512 threads (<=2 each) ----
  const int e0 = tid, e1 = tid + NTHREADS;
  float xr0 = 0.f, xr1 = 0.f;
  auto xfetch = [&](int t0) {
    auto ld = [&](int e) -> float {
      const int tau = e / F, f = e % F;
      int t = t0 + tau; if (t > T - 1) t = T - 1;
      return (f < D) ? particles[((size_t)b * T + t) * D + f]
                     : weights[(size_t)b * T + t];
    };
    xr0 = ld(e0);
    if (e1 < CHUNK * F) xr1 = ld(e1);
  };
  auto xstage = [&]() {
    xs[(e0 / F) * XSTR + (e0 % F)] = (half_t)xr0;
    if (e1 < CHUNK * F) xs[(e1 / F) * XSTR + (e1 % F)] = (half_t)xr1;
  };

  // ---- chunk gi matmul: X[32x17] @ Wi -> gi_lds f32 (6 MFMA/wave) ----
  auto gi_compute = [&]() {
    f16x8 aX0 = *(const f16x8*)(xs + (jn     ) * XSTR + mg * 8);
    f16x8 aX1 = *(const f16x8*)(xs + (jn + 16) * XSTR + mg * 8);
    f32x4 cr0 = {br, br, br, br}, cz0 = {bz, bz, bz, bz}, cn0 = {0.f,0.f,0.f,0.f};
    f32x4 cr1 = cr0, cz1 = cz0, cn1 = cn0;
    cr0 = MFMA(aX0, wiR, cr0); cz0 = MFMA(aX0, wiZ, cz0); cn0 = MFMA(aX0, wiN, cn0);
    cr1 = MFMA(aX1, wiR, cr1); cz1 = MFMA(aX1, wiZ, cz1); cn1 = MFMA(aX1, wiN, cn1);
    #pragma unroll
    for (int r = 0; r < 4; ++r) {
      const int t0r = mg * 4 + r;             // D row = timestep within chunk
      f32x4 v0 = {cr0[r], cz0[r], cn0[r], 0.f};
      *(f32x4*)(gi_lds + t0r * GSTR + jj * 4) = v0;
      const int t1r = t0r + 16;
      f32x4 v1 = {cr1[r], cz1[r], cn1[r], 0.f};
      *(f32x4*)(gi_lds + t1r * GSTR + jj * 4) = v1;
    }
  };

  // ---- init ----
  float hreg = 0.0f;
  if (tid < H) { hb[0][tid] = (half_t)0.f; hb[1][tid] = (half_t)0.f; }
  for (int i = tid; i < CHUNK * XSTR; i += NTHREADS) xs[i] = (half_t)0.f;
  xfetch(0);
  __syncthreads();          // zeros visible before staging
  xstage();
  xfetch(CHUNK);            // prefetch next chunk
  __syncthreads();          // xs visible
  gi_compute();
  __syncthreads();          // gi visible

  // ---- sequential scan: 1 barrier/step ----
  for (int t0 = 0; t0 < T; t0 += CHUNK) {
    for (int tt = 0; tt < CHUNK; tt += 2) {
      GSTEP(hb[0], hb[1], tt);
      GSTEP(hb[1], hb[0], tt + 1);
    }
    if (t0 + CHUNK < T) {
      xstage();                    // stage chunk t0+32 (regs loaded last time)
      xfetch(t0 + 2 * CHUNK);      // prefetch chunk t0+64 (clamped)
      __syncthreads();             // xs visible
      gi_compute();
      __syncthreads();             // gi visible
    }
  }

  // ---- MLP head (fp32), one batch per block ----
  if (mg == 0 && w < 8) sg[jj] = hreg;
  __syncthreads();

  float a1 = 0.0f;
  if (tid < 256) {
    a1 = b1[tid];
    #pragma unroll 4
    for (int k = 0; k < H; ++k) a1 = fmaf(sg[k], W1[k * 256 + tid], a1);
    a1 = fmaxf(a1, 0.0f);
    sg[256 + tid] = a1;   // disjoint from sg[0..127]
  }
  __syncthreads();

  float a2 = 0.0f;
  if (tid < 256) {
    a2 = b2[tid];
    #pragma unroll 4
    for (int k = 0; k < 256; ++k) a2 = fmaf(sg[256 + k], W2[k * 256 + tid], a2);
    a2 = fmaxf(a2, 0.0f);
    a2 *= W3[tid];        // W3 is [256,1]
  }
  #pragma unroll
  for (int off = 32; off > 0; off >>= 1) a2 += __shfl_down(a2, off, 64);
  if (tid < 256 && (tid & 63) == 0) red[tid >> 6] = a2;
  __syncthreads();
  if (tid == 0) {
    out[b] = red[0] + red[1] + red[2] + red[3] + b3[0];
    if (b == 0) out[B] = log_std[0];   // second output, flat index 64
  }
}

extern "C" void kernel_launch(void* const* d_in, const int* in_sizes, int n_in,
                              void* d_out, int out_size, void* d_ws, size_t ws_size,
                              hipStream_t stream) {
  const float* particles = (const float*)d_in[0];
  const float* weights   = (const float*)d_in[1];
  const float* Wi      = (const float*)d_in[2];
  const float* Wh      = (const float*)d_in[3];
  const float* bh      = (const float*)d_in[4];
  const float* W1      = (const float*)d_in[5];
  const float* b1      = (const float*)d_in[6];
  const float* W2      = (const float*)d_in[7];
  const float* b2      = (const float*)d_in[8];
  const float* W3      = (const float*)d_in[9];
  const float* b3      = (const float*)d_in[10];
  const float* log_std = (const float*)d_in[11];

  policy_gru_kernel<<<dim3(B), dim3(NTHREADS), 0, stream>>>(
      particles, weights, Wi, Wh, bh, W1, b1, W2, b2, W3, b3, log_std,
      (float*)d_out);
}

// Round 7
// 2583.680 us; speedup vs baseline: 1.7349x; 1.7349x over previous
//
#include <hip/hip_runtime.h>
#include <hip/hip_bf16.h>
#include <hip/hip_fp8.h>

#define B 64
#define T 8192
#define D 16
#define H 128
#define F 17        // D + 1 features
#define NTHREADS 512
#define CHUNK 32
#define XSTR 40     // xs row stride in halfs (80 B) — bank-friendly
#define GSTR 516    // gi row stride in floats (16B-aligned, conflict-free)

typedef _Float16 half_t;
typedef _Float16 f16x8 __attribute__((ext_vector_type(8)));
typedef float f32x4 __attribute__((ext_vector_type(4)));
typedef int i32x8 __attribute__((ext_vector_type(8)));

#define MFMA(a, b, c) __builtin_amdgcn_mfma_f32_16x16x32_f16((a), (b), (c), 0, 0, 0)
// fp8(e4m3) x fp8(e4m3), K=128, scales = 1.0 in every E8M0 byte
#define MFMAS(a, b, c) \
  __builtin_amdgcn_mfma_scale_f32_16x16x128_f8f6f4((a), (b), (c), 0, 0, 0, 0x7F7F7F7F, 0, 0x7F7F7F7F)

__device__ __forceinline__ float fast_rcp(float x) {
#if __has_builtin(__builtin_amdgcn_rcpf)
  return __builtin_amdgcn_rcpf(x);
#else
  return 1.0f / x;
#endif
}
__device__ __forceinline__ float fast_exp2(float x) {
#if __has_builtin(__builtin_amdgcn_exp2f)
  return __builtin_amdgcn_exp2f(x);
#else
  return exp2f(x);
#endif
}
__device__ __forceinline__ unsigned char f32_to_e4m3(float f) {
  __hip_fp8_e4m3 q(f);
  return __builtin_bit_cast(unsigned char, q);
}

// One GRU step, fp8-MX matvec: 2 LDS reads (A = 32 h-bytes) + 3 MFMA(K=128),
// gates in-lane, h_{t+1} (fp8) -> WB. One barrier per step.
#define GSTEP(RB, WB, TT)                                                    \
  do {                                                                       \
    const f32x4 gv = *(const f32x4*)(gi_lds + ((TT) & 31) * GSTR + jj * 4);  \
    const i32x8 a8 = *(const i32x8*)((RB) + mg * 32);                        \
    f32x4 ar = {gv[0], gv[0], gv[0], gv[0]};                                 \
    f32x4 az = {gv[1], gv[1], gv[1], gv[1]};                                 \
    f32x4 an = {bn2, bn2, bn2, bn2};                                         \
    ar = MFMAS(a8, wb_r, ar);                                                \
    az = MFMAS(a8, wb_z, az);                                                \
    an = MFMAS(a8, wb_n, an);                                                \
    float rr = fast_rcp(1.0f + fast_exp2(-ar[0]));                           \
    float zz = fast_rcp(1.0f + fast_exp2(-az[0]));                           \
    float pre = fmaf(rr, an[0], gv[2]);                                      \
    pre = fminf(fmaxf(pre, -40.0f), 40.0f);                                  \
    float e = fast_exp2(-pre);                                               \
    float nn = (1.0f - e) * fast_rcp(1.0f + e);                              \
    hreg = fmaf(zz, hreg - nn, nn);  /* (1-z)*n + z*h */                     \
    if (mg == 0) (WB)[jj] = f32_to_e4m3(hreg);                               \
    __syncthreads();                                                         \
  } while (0)

__global__ __launch_bounds__(NTHREADS, 1)
void policy_gru_kernel(const float* __restrict__ particles,
                       const float* __restrict__ weights,
                       const float* __restrict__ Wi, const float* __restrict__ Wh,
                       const float* __restrict__ bh,
                       const float* __restrict__ W1, const float* __restrict__ b1,
                       const float* __restrict__ W2, const float* __restrict__ b2,
                       const float* __restrict__ W3, const float* __restrict__ b3,
                       const float* __restrict__ log_std,
                       float* __restrict__ out)
{
  __shared__ __align__(32) unsigned char hb8[2][H];      // h double buffer (fp8)
  __shared__ __align__(16) half_t xs[CHUNK * XSTR];      // staged X chunk (f16)
  __shared__ __align__(16) float gi_lds[CHUNK * GSTR];   // gi[tau][j*4+{r,z,n,pad}]
  __shared__ float sg[NTHREADS];
  __shared__ float red[8];

  const int tid = threadIdx.x;
  const int b   = blockIdx.x;
  const int l   = tid & 63;
  const int w   = tid >> 6;      // wave 0..7 owns cols w*16..w*16+15
  const int mg  = l >> 4;        // k-group 0..3 (32 k each)
  const int jn  = l & 15;
  const int jj  = w * 16 + jn;   // hidden unit owned by this lane

  const float L1 = 1.4426950408889634f;   // log2(e)
  const float L2 = 2.0f * L1;

  // ---- fp8 Wh B-fragments: gate col jj, k = mg*32 + r*4 + byte (prescaled) ----
  auto wload8 = [&](int gate) -> i32x8 {
    const float sc  = (gate == 2) ? L2 : L1;
    const int   col = gate * H + jj;
    i32x8 v;
    #pragma unroll
    for (int r = 0; r < 8; ++r) {
      unsigned int word = 0;
      #pragma unroll
      for (int byt = 0; byt < 4; ++byt) {
        const int k = mg * 32 + r * 4 + byt;
        word |= ((unsigned int)f32_to_e4m3(Wh[k * 384 + col] * sc)) << (8 * byt);
      }
      v[r] = (int)word;
    }
    return v;
  };
  const i32x8 wb_r = wload8(0), wb_z = wload8(1), wb_n = wload8(2);
  const float bn2 = bh[256 + jj] * L2;

  // ---- f16 Wi B-fragments for the chunk gi matmul, K padded 17->32 ----
  auto wiload = [&](int gate) -> f16x8 {
    f16x8 v;
    const float sc  = (gate == 2) ? L2 : L1;
    const int   col = gate * H + jj;
    #pragma unroll
    for (int i = 0; i < 8; ++i) {
      const int k = mg * 8 + i;
      v[i] = (half_t)(k < F ? Wi[k * 384 + col] * sc : 0.0f);
    }
    return v;
  };
  const f16x8 wiR = wiload(0), wiZ = wiload(1), wiN = wiload(2);
  const float br = bh[jj] * L1, bz = bh[128 + jj] * L1;

  // ---- X chunk prefetch: 544 elements over 512 threads (<=2 each) ----
  const int e0 = tid, e1 = tid + NTHREADS;
  float xr0 = 0.f, xr1 = 0.f;
  auto xfetch = [&](int t0) {
    auto ld = [&](int e) -> float {
      const int tau = e / F, f = e % F;
      int t = t0 + tau; if (t > T - 1) t = T - 1;
      return (f < D) ? particles[((size_t)b * T + t) * D + f]
                     : weights[(size_t)b * T + t];
    };
    xr0 = ld(e0);
    if (e1 < CHUNK * F) xr1 = ld(e1);
  };
  auto xstage = [&]() {
    xs[(e0 / F) * XSTR + (e0 % F)] = (half_t)xr0;
    if (e1 < CHUNK * F) xs[(e1 / F) * XSTR + (e1 % F)] = (half_t)xr1;
  };

  // ---- chunk gi matmul: X[32x17] @ Wi -> gi_lds f32 (6 f16-MFMA/wave) ----
  auto gi_compute = [&]() {
    f16x8 aX0 = *(const f16x8*)(xs + (jn     ) * XSTR + mg * 8);
    f16x8 aX1 = *(const f16x8*)(xs + (jn + 16) * XSTR + mg * 8);
    f32x4 cr0 = {br, br, br, br}, cz0 = {bz, bz, bz, bz}, cn0 = {0.f,0.f,0.f,0.f};
    f32x4 cr1 = cr0, cz1 = cz0, cn1 = cn0;
    cr0 = MFMA(aX0, wiR, cr0); cz0 = MFMA(aX0, wiZ, cz0); cn0 = MFMA(aX0, wiN, cn0);
    cr1 = MFMA(aX1, wiR, cr1); cz1 = MFMA(aX1, wiZ, cz1); cn1 = MFMA(aX1, wiN, cn1);
    #pragma unroll
    for (int r = 0; r < 4; ++r) {
      const int t0r = mg * 4 + r;             // D row = timestep within chunk
      f32x4 v0 = {cr0[r], cz0[r], cn0[r], 0.f};
      *(f32x4*)(gi_lds + t0r * GSTR + jj * 4) = v0;
      const int t1r = t0r + 16;
      f32x4 v1 = {cr1[r], cz1[r], cn1[r], 0.f};
      *(f32x4*)(gi_lds + t1r * GSTR + jj * 4) = v1;
    }
  };

  // ---- init ----
  float hreg = 0.0f;
  if (tid < H) { hb8[0][tid] = 0; hb8[1][tid] = 0; }   // fp8 zero = 0x00
  for (int i = tid; i < CHUNK * XSTR; i += NTHREADS) xs[i] = (half_t)0.f;
  xfetch(0);
  __syncthreads();          // zeros visible before staging
  xstage();
  xfetch(CHUNK);            // prefetch next chunk
  __syncthreads();          // xs visible
  gi_compute();
  __syncthreads();          // gi visible

  // ---- sequential scan: 1 barrier/step, 3 MX-MFMA/wave/step ----
  for (int t0 = 0; t0 < T; t0 += CHUNK) {
    for (int tt = 0; tt < CHUNK; tt += 2) {
      GSTEP(hb8[0], hb8[1], tt);
      GSTEP(hb8[1], hb8[0], tt + 1);
    }
    if (t0 + CHUNK < T) {
      xstage();                    // stage chunk t0+32 (regs loaded last time)
      xfetch(t0 + 2 * CHUNK);      // prefetch chunk t0+64 (clamped)
      __syncthreads();             // xs visible
      gi_compute();
      __syncthreads();             // gi visible
    }
  }

  // ---- MLP head (fp32), one batch per block ----
  if (mg == 0) sg[jj] = hreg;
  __syncthreads();

  float a1 = 0.0f;
  if (tid < 256) {
    a1 = b1[tid];
    #pragma unroll 4
    for (int k = 0; k < H; ++k) a1 = fmaf(sg[k], W1[k * 256 + tid], a1);
    a1 = fmaxf(a1, 0.0f);
    sg[256 + tid] = a1;   // disjoint from sg[0..127]
  }
  __syncthreads();

  float a2 = 0.0f;
  if (tid < 256) {
    a2 = b2[tid];
    #pragma unroll 4
    for (int k = 0; k < 256; ++k) a2 = fmaf(sg[256 + k], W2[k * 256 + tid], a2);
    a2 = fmaxf(a2, 0.0f);
    a2 *= W3[tid];        // W3 is [256,1]
  }
  #pragma unroll
  for (int off = 32; off > 0; off >>= 1) a2 += __shfl_down(a2, off, 64);
  if (tid < 256 && (tid & 63) == 0) red[tid >> 6] = a2;
  __syncthreads();
  if (tid == 0) {
    out[b] = red[0] + red[1] + red[2] + red[3] + b3[0];
    if (b == 0) out[B] = log_std[0];   // second output, flat index 64
  }
}

extern "C" void kernel_launch(void* const* d_in, const int* in_sizes, int n_in,
                              void* d_out, int out_size, void* d_ws, size_t ws_size,
                              hipStream_t stream) {
  const float* particles = (const float*)d_in[0];
  const float* weights   = (const float*)d_in[1];
  const float* Wi      = (const float*)d_in[2];
  const float* Wh      = (const float*)d_in[3];
  const float* bh      = (const float*)d_in[4];
  const float* W1      = (const float*)d_in[5];
  const float* b1      = (const float*)d_in[6];
  const float* W2      = (const float*)d_in[7];
  const float* b2      = (const float*)d_in[8];
  const float* W3      = (const float*)d_in[9];
  const float* b3      = (const float*)d_in[10];
  const float* log_std = (const float*)d_in[11];

  policy_gru_kernel<<<dim3(B), dim3(NTHREADS), 0, stream>>>(
      particles, weights, Wi, Wh, bh, W1, b1, W2, b2, W3, b3, log_std,
      (float*)d_out);
}